// Round 7
// baseline (1483.160 us; speedup 1.0000x reference)
//
#include <hip/hip_runtime.h>
#include <hip/hip_bf16.h>
#include <math.h>

typedef unsigned short u16;
typedef unsigned int u32;
typedef __bf16 bf16x8 __attribute__((ext_vector_type(8)));
typedef float f32x4 __attribute__((ext_vector_type(4)));

#define MROWS 100352   // 32 * 56 * 56
#define CDIM 512
#define SCALE_ATTN 0.17677669529663687f

__device__ __forceinline__ u16 f2bf(float f) {
    u32 u = __float_as_uint(f);
    u32 r = (u + 0x7fffu + ((u >> 16) & 1u)) >> 16;   // RNE
    return (u16)r;
}
__device__ __forceinline__ float bf2f(u16 h) {
    return __uint_as_float(((u32)h) << 16);
}

// ---------------- transpose + cast: fp32 W[K][N] -> bf16 WT[N][K] ----------------
__global__ void transpose_cast(const float* __restrict__ W, u16* __restrict__ WT, int K, int N) {
    int idx = blockIdx.x * 256 + threadIdx.x;
    if (idx >= K * N) return;
    int k = idx / N, n = idx % N;
    WT[(size_t)n * K + k] = f2bf(W[idx]);
}

// ---------------- LayerNorm fp32 -> bf16, one wave per row (C=512) ----------------
__global__ __launch_bounds__(256) void ln_kernel(const float* __restrict__ x, const float* __restrict__ g,
                                                 const float* __restrict__ bta, u16* __restrict__ out) {
    int row = blockIdx.x * 4 + (threadIdx.x >> 6);
    int lane = threadIdx.x & 63;
    const float* xr = x + (size_t)row * CDIM + lane * 8;
    float4 v0 = *(const float4*)xr;
    float4 v1 = *(const float4*)(xr + 4);
    float xv[8] = {v0.x, v0.y, v0.z, v0.w, v1.x, v1.y, v1.z, v1.w};
    float s = 0.f, ss = 0.f;
#pragma unroll
    for (int i = 0; i < 8; ++i) { s += xv[i]; ss += xv[i] * xv[i]; }
#pragma unroll
    for (int o = 1; o < 64; o <<= 1) { s += __shfl_xor(s, o); ss += __shfl_xor(ss, o); }
    float mu = s * (1.f / CDIM);
    float var = ss * (1.f / CDIM) - mu * mu;
    float rs = rsqrtf(var + 1e-6f);
    int c = lane * 8;
    u32 pk[4];
#pragma unroll
    for (int i = 0; i < 4; ++i) {
        float y0 = (xv[2 * i] - mu) * rs * g[c + 2 * i] + bta[c + 2 * i];
        float y1 = (xv[2 * i + 1] - mu) * rs * g[c + 2 * i + 1] + bta[c + 2 * i + 1];
        pk[i] = (u32)f2bf(y0) | ((u32)f2bf(y1) << 16);
    }
    uint4 ov; ov.x = pk[0]; ov.y = pk[1]; ov.z = pk[2]; ov.w = pk[3];
    *(uint4*)(out + (size_t)row * CDIM + c) = ov;
}

// ---------------- bf16 GEMM: C[M,N] = A[M,K] * BT[N,K]^T ----------------
// 128x128 tile, BK=64, 4 waves (2x2), 2-buffer 64KB LDS -> 2 blocks/CU.
// Counted-vmcnt pipeline, 2-tile prefetch distance with only 2 buffers via
// issue-after-close: per tile {WAITVM(8); bar; ds_read+MFMA; bar; ISSUE(t+2
// into the buffer this tile just finished reading)}. vmcnt reaches 0 only on
// the last tile. Cross-block TLP (2 blocks/CU) covers barrier/wait stalls.
// XOR swizzle via pre-swizzled global source column + same XOR on ds_read.
#define BM 128
#define BN 128
#define BK 64
#define BUFE (BM * BK + BN * BK)   // 16384 u16 = 32KB per buffer

enum { EPI_BF16 = 0, EPI_GELU_BF16 = 1, EPI_RES_F32 = 2 };

__device__ __forceinline__ void gload_lds16(const void* g, void* l) {
    __builtin_amdgcn_global_load_lds(
        (const __attribute__((address_space(1))) u32*)g,
        (__attribute__((address_space(3))) u32*)l, 16, 0, 0);
}

#define WAITVM8() asm volatile("s_waitcnt vmcnt(8)" ::: "memory")
#define WAITVM0() asm volatile("s_waitcnt vmcnt(0)" ::: "memory")
#define BARRIER() __builtin_amdgcn_s_barrier()
#define SCHEDBAR() __builtin_amdgcn_sched_barrier(0)

__device__ __forceinline__ float gelu_tanh(float x) {
    float y = 0.7978845608028654f * (x + 0.044715f * x * x * x);
    y = fmaxf(y, -20.f);
    float u = __expf(-2.f * y);
    float th = (1.f - u) / (1.f + u);
    return 0.5f * x * (1.f + th);
}

template <int EPI>
__global__ __launch_bounds__(256, 2) void gemm_bt(const u16* __restrict__ A, const u16* __restrict__ BT,
                                                  const float* __restrict__ bias, const float* __restrict__ res,
                                                  void* __restrict__ outp, int M, int N, int K, int nnb) {
    __shared__ __align__(16) u16 smem[2 * BUFE];   // 64 KB

    const int t = threadIdx.x;
    const int lane = t & 63;
    const int w = t >> 6;
    const int wr = w >> 1, wc = w & 1;

    // XCD-bijective swizzle (grid % 8 == 0 for all shapes here), A-panel-major.
    const int nwg = gridDim.x;
    const int chunk = nwg >> 3;
    const int wg = (blockIdx.x & 7) * chunk + (blockIdx.x >> 3);
    const int m0 = (wg / nnb) * BM;
    const int n0 = (wg % nnb) * BN;

    f32x4 acc[4][4] = {};

    const int r15 = lane & 15;
    const int khalf = (lane >> 4) << 3;
    const int xorv = (r15 & 7) << 3;

    // staging coords: 256 threads, 8 threads/row, 32 rows per gload line
    const int srow = t >> 3;                        // 0..31
    const int scol = (((t & 7) ^ (srow & 7)) << 3); // pre-swizzled global column
    const u16* Ag = A + (size_t)(m0 + srow) * K + scol;
    const u16* Bg = BT + (size_t)(n0 + srow) * K + scol;

    const int nt = K / BK;

#define ISSUE(buf_, tile_)                                                           \
    {                                                                                \
        u16* dst_ = smem + (buf_) * BUFE;                                            \
        const int kt_ = (tile_) * BK;                                                \
        _Pragma("unroll")                                                            \
        for (int i = 0; i < 4; ++i)                                                  \
            gload_lds16(Ag + (size_t)(i * 32) * K + kt_, &dst_[i * 2048 + t * 8]);   \
        _Pragma("unroll")                                                            \
        for (int i = 0; i < 4; ++i)                                                  \
            gload_lds16(Bg + (size_t)(i * 32) * K + kt_, &dst_[8192 + i * 2048 + t * 8]); \
    }

    // prologue: tiles 0,1 into buffers 0,1 (16 loads in flight per thread)
    ISSUE(0, 0);
    ISSUE(1, 1);

    for (int tt = 0; tt < nt; ++tt) {
        const int d = tt & 1;

        // tile tt resident: my 8 loads done (8 newest = tile tt+1's may fly);
        // barrier makes ALL waves' tile-tt loads done.
        if (tt + 1 < nt) WAITVM8(); else WAITVM0();
        BARRIER();
        SCHEDBAR();                    // no ds_read hoists above visibility point

        const u16* As = smem + d * BUFE;
        const u16* Bs = As + BM * BK;
        bf16x8 af[4][2], bf[4][2];
#pragma unroll
        for (int mi = 0; mi < 4; ++mi)
#pragma unroll
            for (int kk = 0; kk < 2; ++kk)
                af[mi][kk] = *(const bf16x8*)&As[(wr * 64 + mi * 16 + r15) * BK + ((kk * 32 + khalf) ^ xorv)];
#pragma unroll
        for (int ni = 0; ni < 4; ++ni)
#pragma unroll
            for (int kk = 0; kk < 2; ++kk)
                bf[ni][kk] = *(const bf16x8*)&Bs[(wc * 64 + ni * 16 + r15) * BK + ((kk * 32 + khalf) ^ xorv)];
#pragma unroll
        for (int kk = 0; kk < 2; ++kk)
#pragma unroll
            for (int mi = 0; mi < 4; ++mi)
#pragma unroll
                for (int ni = 0; ni < 4; ++ni)
                    acc[mi][ni] = __builtin_amdgcn_mfma_f32_16x16x32_bf16(af[mi][kk], bf[ni][kk], acc[mi][ni], 0, 0, 0);

        SCHEDBAR();                    // reads stay above the closing barrier
        BARRIER();                     // all waves' reads of buf d retired
        if (tt + 2 < nt) ISSUE(d, tt + 2);   // overwrite the buffer just closed
    }
#undef ISSUE

    // ---- coalesced epilogue: per-wave LDS staging (wave-private, 76-float pad) ----
    float* ep = (float*)smem + w * (16 * 76);
    const int lg = lane >> 4;
#pragma unroll
    for (int mi = 0; mi < 4; ++mi) {
#pragma unroll
        for (int ni = 0; ni < 4; ++ni)
#pragma unroll
            for (int j = 0; j < 4; ++j)
                ep[(lg * 4 + j) * 76 + ni * 16 + r15] = acc[mi][ni][j];
#pragma unroll
        for (int p = 0; p < 4; ++p) {
            int lr = p * 4 + lg;
            f32x4 v = *(f32x4*)&ep[lr * 76 + r15 * 4];
            int grow = m0 + wr * 64 + mi * 16 + lr;
            int gcol = n0 + wc * 64 + r15 * 4;
            float4 bv = *(const float4*)&bias[gcol];
            float o0 = v[0] + bv.x, o1 = v[1] + bv.y, o2 = v[2] + bv.z, o3 = v[3] + bv.w;
            if (EPI == EPI_GELU_BF16) {
                o0 = gelu_tanh(o0); o1 = gelu_tanh(o1); o2 = gelu_tanh(o2); o3 = gelu_tanh(o3);
            }
            if (EPI == EPI_RES_F32) {
                size_t off = (size_t)grow * N + gcol;
                float4 rv = *(const float4*)&res[off];
                float4 ov = make_float4(o0 + rv.x, o1 + rv.y, o2 + rv.z, o3 + rv.w);
                *(float4*)((float*)outp + off) = ov;
            } else {
                uint2 ov;
                ov.x = (u32)f2bf(o0) | ((u32)f2bf(o1) << 16);
                ov.y = (u32)f2bf(o2) | ((u32)f2bf(o3) << 16);
                *(uint2*)((u16*)outp + (size_t)grow * N + gcol) = ov;
            }
        }
    }
}

// ---------------- windowed attention: one wave per (window, head) ----------------
__global__ __launch_bounds__(64) void attn_kernel(const u16* __restrict__ qkv, u16* __restrict__ aout) {
    __shared__ float Ks[49 * 32];
    __shared__ float Vs[49 * 32];
    const int wdw = blockIdx.x;
    const int h = blockIdx.y;
    const int t = threadIdx.x;
    const int b = wdw >> 6, wy = (wdw >> 3) & 7, wx = wdw & 7;

    int row = 0;
    float q[32];
    if (t < 49) {
        int py = t / 7, px = t % 7;
        row = b * 3136 + (wy * 7 + py) * 56 + (wx * 7 + px);
        const u16* bp = qkv + (size_t)row * 1536 + h * 32;
#pragma unroll
        for (int i = 0; i < 4; ++i) {
            uint4 uq = *(const uint4*)(bp + i * 8);
            uint4 uk = *(const uint4*)(bp + 512 + i * 8);
            uint4 uv = *(const uint4*)(bp + 1024 + i * 8);
            u32 qa[4] = {uq.x, uq.y, uq.z, uq.w};
            u32 ka[4] = {uk.x, uk.y, uk.z, uk.w};
            u32 va[4] = {uv.x, uv.y, uv.z, uv.w};
#pragma unroll
            for (int j = 0; j < 4; ++j) {
                q[i * 8 + 2 * j] = bf2f((u16)(qa[j] & 0xffffu));
                q[i * 8 + 2 * j + 1] = bf2f((u16)(qa[j] >> 16));
                Ks[t * 32 + i * 8 + 2 * j] = bf2f((u16)(ka[j] & 0xffffu));
                Ks[t * 32 + i * 8 + 2 * j + 1] = bf2f((u16)(ka[j] >> 16));
                Vs[t * 32 + i * 8 + 2 * j] = bf2f((u16)(va[j] & 0xffffu));
                Vs[t * 32 + i * 8 + 2 * j + 1] = bf2f((u16)(va[j] >> 16));
            }
        }
    }
    __syncthreads();
    if (t >= 49) return;

    float s[49];
    float mx = -1e30f;
    for (int m = 0; m < 49; ++m) {
        float acc = 0.f;
#pragma unroll
        for (int d = 0; d < 32; ++d) acc += q[d] * Ks[m * 32 + d];
        acc *= SCALE_ATTN;
        s[m] = acc;
        mx = fmaxf(mx, acc);
    }
    float sum = 0.f;
    for (int m = 0; m < 49; ++m) { float e = __expf(s[m] - mx); s[m] = e; sum += e; }
    float inv = 1.f / sum;
    float o[32];
#pragma unroll
    for (int d = 0; d < 32; ++d) o[d] = 0.f;
    for (int m = 0; m < 49; ++m) {
        float p = s[m] * inv;
#pragma unroll
        for (int d = 0; d < 32; ++d) o[d] += p * Vs[m * 32 + d];
    }
    u16* op = aout + (size_t)row * 512 + h * 32;
#pragma unroll
    for (int i = 0; i < 4; ++i) {
        uint4 ov;
        ov.x = (u32)f2bf(o[i * 8 + 0]) | ((u32)f2bf(o[i * 8 + 1]) << 16);
        ov.y = (u32)f2bf(o[i * 8 + 2]) | ((u32)f2bf(o[i * 8 + 3]) << 16);
        ov.z = (u32)f2bf(o[i * 8 + 4]) | ((u32)f2bf(o[i * 8 + 5]) << 16);
        ov.w = (u32)f2bf(o[i * 8 + 6]) | ((u32)f2bf(o[i * 8 + 7]) << 16);
        *(uint4*)(op + i * 8) = ov;
    }
}

// ---------------- launch ----------------
extern "C" void kernel_launch(void* const* d_in, const int* in_sizes, int n_in,
                              void* d_out, int out_size, void* d_ws, size_t ws_size,
                              hipStream_t stream) {
    (void)in_sizes; (void)n_in; (void)out_size; (void)ws_size;
    const float* x      = (const float*)d_in[0];
    const float* ln1_g  = (const float*)d_in[1];
    const float* ln1_b  = (const float*)d_in[2];
    const float* qkv_w  = (const float*)d_in[3];
    const float* qkv_b  = (const float*)d_in[4];
    const float* proj_w = (const float*)d_in[5];
    const float* proj_b = (const float*)d_in[6];
    const float* ln2_g  = (const float*)d_in[7];
    const float* ln2_b  = (const float*)d_in[8];
    const float* mlp_w1 = (const float*)d_in[9];
    const float* mlp_b1 = (const float*)d_in[10];
    const float* mlp_w2 = (const float*)d_in[11];
    const float* mlp_b2 = (const float*)d_in[12];
    float* out = (float*)d_out;

    const int M = MROWS;
    char* ws = (char*)d_ws;
    const size_t SZ_H   = (size_t)M * 512 * 2;
    const size_t SZ_X2  = (size_t)M * 512 * 4;
    const size_t SZ_BIG = (size_t)M * 2048 * 2;
    u16*   h    = (u16*)ws;
    float* x2   = (float*)(ws + SZ_H);
    u16*   big  = (u16*)(ws + SZ_H + SZ_X2);
    u16*   qkv_wT  = (u16*)(ws + SZ_H + SZ_X2 + SZ_BIG);
    u16*   proj_wT = qkv_wT + 1536 * 512;
    u16*   w1T     = proj_wT + 512 * 512;
    u16*   w2T     = w1T + 2048 * 512;

    transpose_cast<<<(512 * 1536 + 255) / 256, 256, 0, stream>>>(qkv_w, qkv_wT, 512, 1536);
    transpose_cast<<<(512 * 512 + 255) / 256, 256, 0, stream>>>(proj_w, proj_wT, 512, 512);
    transpose_cast<<<(512 * 2048 + 255) / 256, 256, 0, stream>>>(mlp_w1, w1T, 512, 2048);
    transpose_cast<<<(2048 * 512 + 255) / 256, 256, 0, stream>>>(mlp_w2, w2T, 2048, 512);

    ln_kernel<<<M / 4, 256, 0, stream>>>(x, ln1_g, ln1_b, h);

    gemm_bt<EPI_BF16><<<(M / BM) * (1536 / BN), 256, 0, stream>>>(h, qkv_wT, qkv_b, nullptr, big, M, 1536, 512, 1536 / BN);

    attn_kernel<<<dim3(2048, 16), 64, 0, stream>>>(big, h);

    gemm_bt<EPI_RES_F32><<<(M / BM) * (512 / BN), 256, 0, stream>>>(h, proj_wT, proj_b, x, x2, M, 512, 512, 512 / BN);

    ln_kernel<<<M / 4, 256, 0, stream>>>(x2, ln2_g, ln2_b, h);

    gemm_bt<EPI_GELU_BF16><<<(M / BM) * (2048 / BN), 256, 0, stream>>>(h, w1T, mlp_b1, nullptr, big, M, 2048, 512, 2048 / BN);

    gemm_bt<EPI_RES_F32><<<(M / BM) * (512 / BN), 256, 0, stream>>>(big, w2T, mlp_b2, x2, out, M, 512, 2048, 512 / BN);
}